// Round 3
// baseline (19983.388 us; speedup 1.0000x reference)
//
#include <hip/hip_runtime.h>
#include <math.h>

// Problem constants
#define T_IN   256
#define T_OUT  256
#define D_     128
#define U_     256
#define NSTEP  511

// Distributed design: 8 groups x 4 chains; 16 WGs per group; 256 threads/WG
#define NWG    16
#define NCH    4
#define NGRP   8
#define THREADS 256

// ws (u32 units) layout per group, stride 4096 u32 (16 KB):
//   [0..255]     flags: 16 flags, each padded to 16 u32 (64B)
//   [256..3327]  g_h:   [2 parity][3 layer][4 ch][128 pairs]
//   [3328..3839] g_pred:[2 parity][4 ch][64 pairs]
#define GRPSTRIDE 4096
#define WS_NEED   (NGRP * GRPSTRIDE * 4)

typedef _Float16 half8 __attribute__((ext_vector_type(8)));
typedef float    f32x4 __attribute__((ext_vector_type(4)));

__device__ __forceinline__ float sigmoidf_(float x) {
    return 1.0f / (1.0f + __expf(-x));
}
__device__ __forceinline__ unsigned pk(float a, float b) {
    union { _Float16 h[2]; unsigned u; } v;
    v.h[0] = (_Float16)a; v.h[1] = (_Float16)b; return v.u;
}
__device__ __forceinline__ float2 upk(unsigned x) {
    union { unsigned u; _Float16 h[2]; } v; v.u = x;
    return make_float2((float)v.h[0], (float)v.h[1]);
}

__global__ void zero_ws(unsigned* p, int n) {
    int i = blockIdx.x * 256 + threadIdx.x;
    if (i < n) p[i] = 0;
}

// MFMA 16x16x32 f16 fragment mapping (m89-verified, dtype-independent):
//   A (16x32): lane l holds A[l%16][8*(l/16)+e], e=0..7
//   B (32x16): lane l holds B[8*(l/16)+e][l%16]
//   C (16x16): lane l reg r holds C[(l/16)*4+r][l%16]
// Rows of A = chains (4 real, rows 4..15 duplicates); cols of B = gate cols.
__device__ __forceinline__ void mm_layer(
    const _Float16* __restrict__ wmat, const int wstride, const int nkw,
    const _Float16* __restrict__ umat,
    const unsigned* __restrict__ xsrc, const int xstr,
    const unsigned* __restrict__ hsrc,
    float* __restrict__ sgx_, float* __restrict__ sgh_,
    const int lane, const int gate)
{
    const int u16 = lane & 15, kg = lane >> 4, ch = u16 & 3;
    f32x4 ax = {0.f, 0.f, 0.f, 0.f}, ah = {0.f, 0.f, 0.f, 0.f};
    const _Float16* wb = wmat + (gate * 16 + u16) * wstride + kg * 8;
    const unsigned*  xb = xsrc + ch * xstr + kg * 4;
    for (int ks = 0; ks < nkw; ++ks) {
        half8 a  = *(const half8*)(const void*)(xb + ks * 16);
        half8 bf = *(const half8*)(const void*)(wb + ks * 32);
        ax = __builtin_amdgcn_mfma_f32_16x16x32_f16(a, bf, ax, 0, 0, 0);
    }
    const _Float16* ub = umat + (gate * 16 + u16) * 264 + kg * 8;
    const unsigned*  hb = hsrc + ch * 128 + kg * 4;
    for (int ks = 0; ks < 8; ++ks) {
        half8 a  = *(const half8*)(const void*)(hb + ks * 16);
        half8 bf = *(const half8*)(const void*)(ub + ks * 32);
        ah = __builtin_amdgcn_mfma_f32_16x16x32_f16(a, bf, ah, 0, 0, 0);
    }
    if (lane < 16) {
        #pragma unroll
        for (int r = 0; r < 4; ++r) {
            sgx_[(gate * 16 + u16) * 4 + r] = ax[r];
            sgh_[(gate * 16 + u16) * 4 + r] = ah[r];
        }
    }
}

__device__ __forceinline__ void hop(unsigned* flags, int w, int t, unsigned seq) {
    __syncthreads();                      // drains all prior stores (vmcnt 0)
    if (t == 0) {
        __threadfence();
        __hip_atomic_store(flags + w * 16, seq, __ATOMIC_RELAXED, __HIP_MEMORY_SCOPE_AGENT);
    }
    if (t < NWG) {
        unsigned it = 0;
        while (__hip_atomic_load(flags + t * 16, __ATOMIC_RELAXED, __HIP_MEMORY_SCOPE_AGENT) < seq) {
            if (++it > (1u << 24)) break;  // safety valve: corrupt loudly, never hang
            __builtin_amdgcn_s_sleep(1);
        }
    }
    __syncthreads();
    __threadfence();
}

__global__ __launch_bounds__(THREADS) void gru_dist(
    const float* __restrict__ inputs, const float* __restrict__ noise,
    const float* __restrict__ h_init,
    const float* __restrict__ W0, const float* __restrict__ U0, const float* __restrict__ b0,
    const float* __restrict__ W1, const float* __restrict__ U1, const float* __restrict__ b1,
    const float* __restrict__ W2, const float* __restrict__ U2, const float* __restrict__ b2,
    const float* __restrict__ Wd, const float* __restrict__ bd,
    unsigned* __restrict__ ws, float* __restrict__ out)
{
    const int bid  = blockIdx.x;
    const int grp  = bid >> 4;      // group 0..7
    const int w    = bid & 15;      // wg-in-group 0..15
    const int t    = threadIdx.x;
    const int lane = t & 63;
    const int wv   = t >> 6;

    // ---- LDS (~155 KB total) ----
    __shared__ __align__(16) _Float16 lw0[48 * 136];   // K=128 (+8 pad)
    __shared__ __align__(16) _Float16 lu0[48 * 264];   // K=256 (+8 pad)
    __shared__ __align__(16) _Float16 lw1[48 * 264];
    __shared__ __align__(16) _Float16 lu1[48 * 264];
    __shared__ __align__(16) _Float16 lw2[48 * 264];
    __shared__ __align__(16) _Float16 lu2[48 * 264];
    __shared__ __align__(16) _Float16 lwd[9 * 264];    // 8 cols + zero row
    __shared__ __align__(16) unsigned sx0[NCH][64];    // layer-0 input pairs (D=128)
    __shared__ __align__(16) unsigned sh[3][NCH][128]; // h pairs per layer
    __shared__ __align__(16) unsigned sx2[NCH][128];
    __shared__ __align__(16) unsigned sx3[NCH][128];
    __shared__ float sgx[3 * 16 * 4];                  // [gate][u16][ch]
    __shared__ float sgh[3 * 16 * 4];
    __shared__ float sb[3][2][48];                     // biases for own cols
    __shared__ float sbd[8];
    __shared__ float spo[NCH][8];                      // dense outputs

    unsigned* gbase  = ws + grp * GRPSTRIDE;
    unsigned* gflags = gbase;
    unsigned* g_h    = gbase + 256;
    unsigned* g_pred = gbase + 3328;

    // ---- one-time preload: gather own weight slice fp32->fp16 into LDS ----
    {
        const float* srcs[6] = {W0, U0, W1, U1, W2, U2};
        _Float16*    dsts[6] = {lw0, lu0, lw1, lu1, lw2, lu2};
        const int Ks[6] = {128, 256, 256, 256, 256, 256};
        const int Ss[6] = {136, 264, 264, 264, 264, 264};
        for (int m = 0; m < 6; ++m) {
            const float* s = srcs[m]; _Float16* d = dsts[m];
            const int K = Ks[m], S = Ss[m];
            for (int idx = t; idx < 48 * K; idx += THREADS) {
                int c = idx / K, k = idx - c * K;
                int g = ((c >> 4) << 8) + (w << 4) + (c & 15);
                d[c * S + k] = (_Float16)s[k * 768 + g];
            }
        }
        for (int idx = t; idx < 8 * 256; idx += THREADS) {
            int d0 = idx >> 8, k = idx & 255;
            lwd[d0 * 264 + k] = (_Float16)Wd[k * 128 + (w << 3) + d0];
        }
        for (int idx = t; idx < 264; idx += THREADS) lwd[8 * 264 + idx] = (_Float16)0.f;
        const float* bsrc[3] = {b0, b1, b2};
        for (int idx = t; idx < 288; idx += THREADS) {
            int l = idx / 96, r = idx - l * 96, which = r / 48, c = r - which * 48;
            int g = ((c >> 4) << 8) + (w << 4) + (c & 15);
            sb[l][which][c] = bsrc[l][which * 768 + g];
        }
        if (t < 8) sbd[t] = bd[(w << 3) + t];
        for (int idx = t; idx < 3 * NCH * 128; idx += THREADS) {
            int l = idx >> 9, r = idx & 511, ch = r >> 7, p = r & 127;
            sh[l][ch][p] = pk(h_init[l * 256 + 2 * p], h_init[l * 256 + 2 * p + 1]);
        }
    }
    // finalize threads carry fp32 h state in registers
    float hr[3][2];
    if (t < 32) {
        int pl = t & 7;
        #pragma unroll
        for (int l = 0; l < 3; ++l) {
            hr[l][0] = h_init[l * 256 + 2 * ((w << 3) + pl)];
            hr[l][1] = h_init[l * 256 + 2 * ((w << 3) + pl) + 1];
        }
    }
    __syncthreads();

    unsigned seq = 0;
    for (int ts = 0; ts < NSTEP; ++ts) {
        const int par = ts & 1;

        if (ts < T_IN) {        // warmup input: inputs + noise
            {
                int ch = t >> 6, p = t & 63;
                const float* ip = inputs + ((size_t)(grp * NCH + ch) * T_IN + ts) * D_ + 2 * p;
                const float* np = noise  + ((size_t)(grp * NCH + ch) * T_IN + ts) * D_ + 2 * p;
                sx0[ch][p] = pk(ip[0] + np[0], ip[1] + np[1]);
            }
            __syncthreads();
        }
        // (AR: sx0 already filled from pred read at end of previous step)

        #pragma unroll 1
        for (int l = 0; l < 3; ++l) {
            // ---- gate matmul (waves 0..2 = gates z,r,n) ----
            if (wv < 3) {
                if (l == 0)
                    mm_layer(lw0, 136, 4, lu0, &sx0[0][0], 64,  &sh[0][0][0], sgx, sgh, lane, wv);
                else if (l == 1)
                    mm_layer(lw1, 264, 8, lu1, &sh[0][0][0], 128, &sh[1][0][0], sgx, sgh, lane, wv);
                else
                    mm_layer(lw2, 264, 8, lu2, &sx2[0][0], 128, &sh[2][0][0], sgx, sgh, lane, wv);
            }
            __syncthreads();
            // ---- finalize: 32 threads own (ch, unit-pair) ----
            if (t < 32) {
                int ch = t >> 3, pl = t & 7, gpi = (w << 3) + pl;
                float hn2[2];
                #pragma unroll
                for (int i = 0; i < 2; ++i) {
                    int lu = 2 * pl + i;
                    float gxz = sgx[(0 * 16 + lu) * 4 + ch] + sb[l][0][lu];
                    float ghz = sgh[(0 * 16 + lu) * 4 + ch] + sb[l][1][lu];
                    float gxr = sgx[(1 * 16 + lu) * 4 + ch] + sb[l][0][16 + lu];
                    float ghr = sgh[(1 * 16 + lu) * 4 + ch] + sb[l][1][16 + lu];
                    float gxn = sgx[(2 * 16 + lu) * 4 + ch] + sb[l][0][32 + lu];
                    float ghn = sgh[(2 * 16 + lu) * 4 + ch] + sb[l][1][32 + lu];
                    float z = sigmoidf_(gxz + ghz);
                    float r = sigmoidf_(gxr + ghr);
                    float n = tanhf(gxn + r * ghn);
                    float h = z * hr[l][i] + (1.f - z) * n;
                    hr[l][i] = h; hn2[i] = h;
                }
                unsigned pv = pk(hn2[0], hn2[1]);
                sh[l][ch][gpi] = pv;
                __hip_atomic_store(&g_h[par * 1536 + l * 512 + ch * 128 + gpi], pv,
                                   __ATOMIC_RELAXED, __HIP_MEMORY_SCOPE_AGENT);
            }
            hop(gflags, w, t, ++seq);
            // ---- read other WGs' h slices ----
            for (int idx = t; idx < 480; idx += THREADS) {
                int i = idx >> 5, rem = idx & 31, ch = rem >> 3, pl = rem & 7;
                int src = i + (i >= w);
                int gpi = (src << 3) + pl;
                sh[l][ch][gpi] = __hip_atomic_load(&g_h[par * 1536 + l * 512 + ch * 128 + gpi],
                                                   __ATOMIC_RELAXED, __HIP_MEMORY_SCOPE_AGENT);
            }
            __syncthreads();
            if (l == 1) {       // x2 = h1 + x1 (x1 = h0)
                for (int idx = t; idx < 512; idx += THREADS) {
                    int ch = idx >> 7, p = idx & 127;
                    float2 a = upk(sh[1][ch][p]);
                    float2 xb = upk(sh[0][ch][p]);
                    sx2[ch][p] = pk(a.x + xb.x, a.y + xb.y);
                }
                __syncthreads();
            }
            if (l == 2 && ts >= T_IN - 1) {   // x3 = h2 + x2 (only when dense needed)
                for (int idx = t; idx < 512; idx += THREADS) {
                    int ch = idx >> 7, p = idx & 127;
                    float2 a = upk(sh[2][ch][p]);
                    float2 xb = upk(sx2[ch][p]);
                    sx3[ch][p] = pk(a.x + xb.x, a.y + xb.y);
                }
                __syncthreads();
            }
        }

        // ---- dense readout + AR feedback ----
        if (ts >= T_IN - 1) {
            if (wv == 0) {
                const int u16 = lane & 15, kg = lane >> 4, ch = u16 & 3;
                f32x4 acc = {0.f, 0.f, 0.f, 0.f};
                const _Float16* wb = lwd + (u16 < 8 ? u16 : 8) * 264 + kg * 8;
                const unsigned*  xb = &sx3[ch][0] + kg * 4;
                for (int ks = 0; ks < 8; ++ks) {
                    half8 a  = *(const half8*)(const void*)(xb + ks * 16);
                    half8 bf = *(const half8*)(const void*)(wb + ks * 32);
                    acc = __builtin_amdgcn_mfma_f32_16x16x32_f16(a, bf, acc, 0, 0, 0);
                }
                if (lane < 8) {
                    #pragma unroll
                    for (int r = 0; r < 4; ++r) spo[r][lane] = acc[r] + sbd[lane];
                }
            }
            __syncthreads();
            if (t < 32) {   // store outputs
                int ch = t >> 3, d0 = t & 7;
                out[((size_t)(grp * NCH + ch) * T_OUT + (ts - (T_IN - 1))) * D_ + (w << 3) + d0]
                    = spo[ch][d0];
            }
            if (ts < NSTEP - 1) {   // publish pred as next-step input
                if (t < 16) {
                    int ch = t >> 2, dp = t & 3;
                    unsigned pv = pk(spo[ch][2 * dp], spo[ch][2 * dp + 1]);
                    sx0[ch][(w << 2) + dp] = pv;
                    __hip_atomic_store(&g_pred[par * 256 + ch * 64 + (w << 2) + dp], pv,
                                       __ATOMIC_RELAXED, __HIP_MEMORY_SCOPE_AGENT);
                }
                hop(gflags, w, t, ++seq);
                if (t < 240) {
                    int i = t >> 4, rem = t & 15, ch = rem >> 2, dp = rem & 3;
                    int src = i + (i >= w);
                    sx0[ch][(src << 2) + dp] =
                        __hip_atomic_load(&g_pred[par * 256 + ch * 64 + (src << 2) + dp],
                                          __ATOMIC_RELAXED, __HIP_MEMORY_SCOPE_AGENT);
                }
                __syncthreads();
            }
        }
    }
}

// ---- fallback: round-1 verified fp32 kernel (no ws requirements) ----
__global__ __launch_bounds__(768) void gru_ar_fp32(
    const float* __restrict__ inputs, const float* __restrict__ noise,
    const float* __restrict__ h_init,
    const float* __restrict__ W0, const float* __restrict__ U0, const float* __restrict__ b0,
    const float* __restrict__ W1, const float* __restrict__ U1, const float* __restrict__ b1,
    const float* __restrict__ W2, const float* __restrict__ U2, const float* __restrict__ b2,
    const float* __restrict__ Wd, const float* __restrict__ bd,
    float* __restrict__ out)
{
    const int b = blockIdx.x;
    const int j = threadIdx.x;
    __shared__ float s_x[U_];
    __shared__ float s_h[3][U_];
    __shared__ float s_gz[U_], s_gr[U_], s_gxn[U_], s_ghn[U_];
    __shared__ float s_pred[D_];
    if (j < U_) {
        s_h[0][j] = h_init[0 * U_ + j];
        s_h[1][j] = h_init[1 * U_ + j];
        s_h[2][j] = h_init[2 * U_ + j];
    }
    __syncthreads();
    const float* Ws[3]  = {W0, W1, W2};
    const float* Us[3]  = {U0, U1, U2};
    const float* bss[3] = {b0, b1, b2};
    for (int ts = 0; ts < NSTEP; ++ts) {
        if (j < D_) {
            if (ts < T_IN) {
                const int idx = (b * T_IN + ts) * D_ + j;
                s_x[j] = inputs[idx] + noise[idx];
            } else s_x[j] = s_pred[j];
        }
        __syncthreads();
        #pragma unroll
        for (int l = 0; l < 3; ++l) {
            const int K = (l == 0) ? D_ : U_;
            const float* W = Ws[l]; const float* Urec = Us[l]; const float* bias = bss[l];
            float gx = bias[j];
            for (int k = 0; k < K; ++k) gx = fmaf(s_x[k], W[k * 768 + j], gx);
            float gh = bias[768 + j];
            for (int k = 0; k < U_; ++k) gh = fmaf(s_h[l][k], Urec[k * 768 + j], gh);
            if (j < U_)            s_gz[j] = gx + gh;
            else if (j < 2 * U_)   s_gr[j - U_] = gx + gh;
            else { s_gxn[j - 2 * U_] = gx; s_ghn[j - 2 * U_] = gh; }
            __syncthreads();
            if (j < U_) {
                const float z = sigmoidf_(s_gz[j]);
                const float r = sigmoidf_(s_gr[j]);
                const float n = tanhf(s_gxn[j] + r * s_ghn[j]);
                const float h_new = z * s_h[l][j] + (1.0f - z) * n;
                s_h[l][j] = h_new;
                s_x[j] = (l == 0) ? h_new : (h_new + s_x[j]);
            }
            __syncthreads();
        }
        if (ts >= T_IN - 1) {
            if (j < D_) {
                float p = bd[j];
                for (int k = 0; k < U_; ++k) p = fmaf(s_x[k], Wd[k * D_ + j], p);
                s_pred[j] = p;
                out[(b * T_OUT + (ts - (T_IN - 1))) * D_ + j] = p;
            }
            __syncthreads();
        }
    }
}

extern "C" void kernel_launch(void* const* d_in, const int* in_sizes, int n_in,
                              void* d_out, int out_size, void* d_ws, size_t ws_size,
                              hipStream_t stream) {
    const float* inputs = (const float*)d_in[0];
    const float* noise  = (const float*)d_in[1];
    const float* h_init = (const float*)d_in[2];
    const float* W0 = (const float*)d_in[3];
    const float* U0 = (const float*)d_in[4];
    const float* b0 = (const float*)d_in[5];
    const float* W1 = (const float*)d_in[6];
    const float* U1 = (const float*)d_in[7];
    const float* b1 = (const float*)d_in[8];
    const float* W2 = (const float*)d_in[9];
    const float* U2 = (const float*)d_in[10];
    const float* b2 = (const float*)d_in[11];
    const float* Wd = (const float*)d_in[12];
    const float* bd = (const float*)d_in[13];
    float* out = (float*)d_out;

    if (ws_size >= (size_t)WS_NEED) {
        const int n = NGRP * GRPSTRIDE;
        zero_ws<<<(n + 255) / 256, 256, 0, stream>>>((unsigned*)d_ws, n);
        gru_dist<<<NGRP * NWG, THREADS, 0, stream>>>(
            inputs, noise, h_init, W0, U0, b0, W1, U1, b1, W2, U2, b2, Wd, bd,
            (unsigned*)d_ws, out);
    } else {
        gru_ar_fp32<<<32, 768, 0, stream>>>(
            inputs, noise, h_init, W0, U0, b0, W1, U1, b1, W2, U2, b2, Wd, bd, out);
    }
}

// Round 4
// 6343.592 us; speedup vs baseline: 3.1502x; 3.1502x over previous
//
#include <hip/hip_runtime.h>
#include <math.h>

// Problem constants
#define T_IN   256
#define T_OUT  256
#define D_     128
#define U_     256
#define NSTEP  511

// 8 groups x 4 chains; 16 WGs per group; 256 threads/WG
#define NWG    16
#define NCH    4
#define NGRP   8
#define THREADS 256

// ws layout per group (u32 units, stride 4096 = 16KB):
//   [0..255]      flags: 16 flags padded to 16 u32 (64B) each
//   [256..1791]   g_h:   [3 layer][4 ch][128 pairs] (single-buffered; proof in notes)
//   [1792..2815]  g_pred:[2 parity][4 ch][128] fp32 partial sums (atomicAdd)
#define GRPSTRIDE 4096
#define WS_NEED   (NGRP * GRPSTRIDE * 4)

typedef _Float16 half8 __attribute__((ext_vector_type(8)));
typedef float    f32x4 __attribute__((ext_vector_type(4)));

__device__ __forceinline__ float sigmoidf_(float x) { return 1.0f / (1.0f + __expf(-x)); }
__device__ __forceinline__ unsigned pk(float a, float b) {
    union { _Float16 h[2]; unsigned u; } v;
    v.h[0] = (_Float16)a; v.h[1] = (_Float16)b; return v.u;
}
__device__ __forceinline__ float2 upk(unsigned x) {
    union { unsigned u; _Float16 h[2]; } v; v.u = x;
    return make_float2((float)v.h[0], (float)v.h[1]);
}

__global__ void zero_ws(unsigned* p, int n) {
    int i = blockIdx.x * 256 + threadIdx.x;
    if (i < n) p[i] = 0;
}

// K-accumulating MFMA helper. xb: packed-pair activations (u32*), wb: col-major
// fp16 weights (8 k-elems contiguous per col). One 16x16x32 MFMA per ks.
__device__ __forceinline__ f32x4 mm_k(const unsigned* xb, const _Float16* wb,
                                      int nks, f32x4 acc) {
    #pragma unroll
    for (int ks = 0; ks < nks; ++ks) {
        half8 a = *(const half8*)(const void*)(xb + ks * 16);
        half8 b = *(const half8*)(const void*)(wb + ks * 32);
        acc = __builtin_amdgcn_mfma_f32_16x16x32_f16(a, b, acc, 0, 0, 0);
    }
    return acc;
}

__global__ __launch_bounds__(THREADS) void gru_dist(
    const float* __restrict__ inputs, const float* __restrict__ noise,
    const float* __restrict__ h_init,
    const float* __restrict__ W0, const float* __restrict__ U0, const float* __restrict__ b0,
    const float* __restrict__ W1, const float* __restrict__ U1, const float* __restrict__ b1,
    const float* __restrict__ W2, const float* __restrict__ U2, const float* __restrict__ b2,
    const float* __restrict__ Wd, const float* __restrict__ bd,
    unsigned* __restrict__ ws, float* __restrict__ out)
{
    const int bid  = blockIdx.x;
    const int grp  = bid & 7;       // same-XCD grouping heuristic (round-robin XCDs)
    const int w    = bid >> 3;      // wg-in-group 0..15
    const int t    = threadIdx.x;
    const int lane = t & 63;
    const int wv   = t >> 6;
    const int u16  = lane & 15, kg = lane >> 4, ch4 = u16 & 3;

    // ---- LDS (~158 KB) ----
    __shared__ __align__(16) _Float16 lw0[48 * 136];
    __shared__ __align__(16) _Float16 lu0[48 * 264];
    __shared__ __align__(16) _Float16 lw1[48 * 264];
    __shared__ __align__(16) _Float16 lu1[48 * 264];
    __shared__ __align__(16) _Float16 lw2[48 * 264];
    __shared__ __align__(16) _Float16 lu2[48 * 264];
    __shared__ __align__(16) _Float16 lwdk[128 * 32];   // [out n][own-k 0..31], k>=16 zero
    __shared__ __align__(16) _Float16 sxd[16 * 32];     // dense A: rows 0..3 = chains' x3 slice
    __shared__ __align__(16) unsigned sx0[NCH][64];
    __shared__ __align__(16) unsigned sh[3][NCH][128];
    __shared__ __align__(16) unsigned sx2[NCH][128];
    __shared__ float sgx[3 * 16 * 4];
    __shared__ float sgh[3 * 16 * 4];
    __shared__ float sb[3][2][48];
    __shared__ float sbdf[128];

    unsigned* gbase  = ws + grp * GRPSTRIDE;
    unsigned* gflags = gbase;
    unsigned* g_h    = gbase + 256;
    float*    g_predf = (float*)(gbase + 1792);

    // ---- one-time preload ----
    {
        const float* srcs[6] = {W0, U0, W1, U1, W2, U2};
        _Float16*    dsts[6] = {lw0, lu0, lw1, lu1, lw2, lu2};
        const int Ks[6] = {128, 256, 256, 256, 256, 256};
        const int Ss[6] = {136, 264, 264, 264, 264, 264};
        for (int m = 0; m < 6; ++m) {
            const float* s = srcs[m]; _Float16* d = dsts[m];
            const int K = Ks[m], S = Ss[m];
            for (int idx = t; idx < 48 * K; idx += THREADS) {
                int c = idx / K, k = idx - c * K;
                int g = ((c >> 4) << 8) + (w << 4) + (c & 15);
                d[c * S + k] = (_Float16)s[k * 768 + g];
            }
        }
        for (int idx = t; idx < 128 * 32; idx += THREADS) {
            int n = idx >> 5, k = idx & 31;
            lwdk[idx] = (k < 16) ? (_Float16)Wd[(w * 16 + k) * 128 + n] : (_Float16)0.f;
        }
        for (int idx = t; idx < 16 * 32; idx += THREADS) sxd[idx] = (_Float16)0.f;
        const float* bsrc[3] = {b0, b1, b2};
        for (int idx = t; idx < 288; idx += THREADS) {
            int l = idx / 96, r = idx - l * 96, which = r / 48, c = r - which * 48;
            int g = ((c >> 4) << 8) + (w << 4) + (c & 15);
            sb[l][which][c] = bsrc[l][which * 768 + g];
        }
        for (int idx = t; idx < 128; idx += THREADS) sbdf[idx] = bd[idx];
        for (int idx = t; idx < 3 * NCH * 128; idx += THREADS) {
            int l = idx >> 9, r = idx & 511, cc = r >> 7, p = r & 127;
            sh[l][cc][p] = pk(h_init[l * 256 + 2 * p], h_init[l * 256 + 2 * p + 1]);
        }
    }
    float hr[3][2];
    if (t < 32) {
        int pl = t & 7;
        #pragma unroll
        for (int l = 0; l < 3; ++l) {
            hr[l][0] = h_init[l * 256 + 2 * ((w << 3) + pl)];
            hr[l][1] = h_init[l * 256 + 2 * ((w << 3) + pl) + 1];
        }
    }
    __syncthreads();

    auto hop_begin = [&](unsigned s) {
        __syncthreads();   // compiler emits vmcnt(0) before s_barrier: prior stores done
        if (t == 0)
            __hip_atomic_store(&gflags[w * 16], s, __ATOMIC_RELEASE, __HIP_MEMORY_SCOPE_AGENT);
    };
    auto hop_end = [&](unsigned s) {
        if (t < NWG) {
            unsigned it = 0;
            while (__hip_atomic_load(&gflags[t * 16], __ATOMIC_RELAXED,
                                     __HIP_MEMORY_SCOPE_AGENT) < s) {
                if (++it > (1u << 22)) break;   // loud corruption beats a hang
                __builtin_amdgcn_s_sleep(1);
            }
        }
        if (t < 64) __builtin_amdgcn_fence(__ATOMIC_ACQUIRE, "agent");  // 1 inv/WG/hop
        __syncthreads();
    };
    auto gather_h = [&](int l) {
        for (int idx = t; idx < 480; idx += THREADS) {
            int i = idx >> 5, rem = idx & 31, cc = rem >> 3, pl = rem & 7;
            int src = i + (i >= w);
            int gpi = (src << 3) + pl;
            sh[l][cc][gpi] = __hip_atomic_load(&g_h[l * 512 + cc * 128 + gpi],
                                               __ATOMIC_RELAXED, __HIP_MEMORY_SCOPE_AGENT);
        }
    };
    auto finalize = [&](int l, bool dox3) {
        if (t < 32) {
            int cc = t >> 3, pl = t & 7, gpi = (w << 3) + pl;
            float hn2[2];
            #pragma unroll
            for (int i = 0; i < 2; ++i) {
                int lu = 2 * pl + i;
                float gxz = sgx[(0 * 16 + lu) * 4 + cc] + sb[l][0][lu];
                float ghz = sgh[(0 * 16 + lu) * 4 + cc] + sb[l][1][lu];
                float gxr = sgx[(1 * 16 + lu) * 4 + cc] + sb[l][0][16 + lu];
                float ghr = sgh[(1 * 16 + lu) * 4 + cc] + sb[l][1][16 + lu];
                float gxn = sgx[(2 * 16 + lu) * 4 + cc] + sb[l][0][32 + lu];
                float ghn = sgh[(2 * 16 + lu) * 4 + cc] + sb[l][1][32 + lu];
                float z = sigmoidf_(gxz + ghz);
                float r = sigmoidf_(gxr + ghr);
                float n = tanhf(gxn + r * ghn);
                float h = z * hr[l][i] + (1.f - z) * n;
                hr[l][i] = h; hn2[i] = h;
            }
            unsigned pv = pk(hn2[0], hn2[1]);
            sh[l][cc][gpi] = pv;
            __hip_atomic_store(&g_h[l * 512 + cc * 128 + gpi], pv,
                               __ATOMIC_RELAXED, __HIP_MEMORY_SCOPE_AGENT);
            if (dox3) {   // x3 slice for K-split dense (local units only)
                float2 x2p = upk(sx2[cc][gpi]);
                sxd[cc * 32 + 2 * pl]     = (_Float16)(hn2[0] + x2p.x);
                sxd[cc * 32 + 2 * pl + 1] = (_Float16)(hn2[1] + x2p.y);
            }
        }
    };
    auto store_g = [&](f32x4 wa, f32x4 ua) {
        if (lane < 16) {
            #pragma unroll
            for (int r = 0; r < 4; ++r) {
                sgx[(wv * 16 + u16) * 4 + r] = wa[r];
                sgh[(wv * 16 + u16) * 4 + r] = ua[r];
            }
        }
    };

    const f32x4 z4 = {0.f, 0.f, 0.f, 0.f};
    f32x4 ua0 = z4, ua1 = z4, ua2 = z4;
    unsigned seq = 0;

    for (int ts = 0; ts < NSTEP; ++ts) {
        const int par = ts & 1;
        const bool doDense = (ts >= T_IN - 1);

        if (ts < T_IN) {   // warmup input (AR input was filled at end of prev step)
            int cc = t >> 6, p = t & 63;
            const float* ip = inputs + ((size_t)(grp * NCH + cc) * T_IN + ts) * D_ + 2 * p;
            const float* np = noise  + ((size_t)(grp * NCH + cc) * T_IN + ts) * D_ + 2 * p;
            sx0[cc][p] = pk(ip[0] + np[0], ip[1] + np[1]);
            __syncthreads();
        }

        // ---- layer 0 ----  (ua0 = U0·h0(ts-1), from prev hop's overlap)
        if (wv < 3) {
            if (ts == 0)
                ua0 = mm_k(&sh[0][0][0] + ch4 * 128 + kg * 4,
                           lu0 + (wv * 16 + u16) * 264 + kg * 8, 8, z4);
            f32x4 wa = mm_k(&sx0[0][0] + ch4 * 64 + kg * 4,
                            lw0 + (wv * 16 + u16) * 136 + kg * 8, 4, z4);
            store_g(wa, ua0);
        }
        __syncthreads();
        finalize(0, false);
        hop_begin(seq + 1);
        if (wv < 3)   // overlap: U1·h1(ts-1)
            ua1 = mm_k(&sh[1][0][0] + ch4 * 128 + kg * 4,
                       lu1 + (wv * 16 + u16) * 264 + kg * 8, 8, z4);
        if (ts > 0) gather_h(2);   // h2(ts-1): covered by prev step's l2 flags
        hop_end(seq + 1); ++seq;
        gather_h(0);
        __syncthreads();

        // ---- layer 1 ----
        if (wv < 3) {
            f32x4 wa = mm_k(&sh[0][0][0] + ch4 * 128 + kg * 4,
                            lw1 + (wv * 16 + u16) * 264 + kg * 8, 8, z4);
            store_g(wa, ua1);
        }
        __syncthreads();
        finalize(1, false);
        hop_begin(seq + 1);
        if (wv < 3)   // overlap: U2·h2(ts-1) (gathered in previous hop's overlap)
            ua2 = mm_k(&sh[2][0][0] + ch4 * 128 + kg * 4,
                       lu2 + (wv * 16 + u16) * 264 + kg * 8, 8, z4);
        hop_end(seq + 1); ++seq;
        gather_h(1);
        __syncthreads();
        // x2 = h1 + h0 (residual)
        for (int idx = t; idx < 512; idx += THREADS) {
            int cc = idx >> 7, p = idx & 127;
            float2 a = upk(sh[1][cc][p]);
            float2 b = upk(sh[0][cc][p]);
            sx2[cc][p] = pk(a.x + b.x, a.y + b.y);
        }
        __syncthreads();

        // ---- layer 2 ----
        if (wv < 3) {
            f32x4 wa = mm_k(&sx2[0][0] + ch4 * 128 + kg * 4,
                            lw2 + (wv * 16 + u16) * 264 + kg * 8, 8, z4);
            store_g(wa, ua2);
        }
        __syncthreads();
        finalize(2, doDense);
        if (doDense) {
            __syncthreads();   // sxd visible
            // K-split dense: 2 n-tiles per wave, one 16x16x32 MFMA each (k>=16 zero)
            half8 a = *(const half8*)(const void*)(sxd + u16 * 32 + kg * 8);
            int nt0 = 2 * wv;
            half8 bA = *(const half8*)(const void*)(lwdk + (nt0 * 16 + u16) * 32 + kg * 8);
            half8 bB = *(const half8*)(const void*)(lwdk + ((nt0 + 1) * 16 + u16) * 32 + kg * 8);
            f32x4 dA = __builtin_amdgcn_mfma_f32_16x16x32_f16(a, bA, z4, 0, 0, 0);
            f32x4 dB = __builtin_amdgcn_mfma_f32_16x16x32_f16(a, bB, z4, 0, 0, 0);
            if (lane < 16) {
                #pragma unroll
                for (int r = 0; r < 4; ++r) {
                    __hip_atomic_fetch_add(&g_predf[par * 512 + r * 128 + nt0 * 16 + u16],
                                           dA[r], __ATOMIC_RELAXED, __HIP_MEMORY_SCOPE_AGENT);
                    __hip_atomic_fetch_add(&g_predf[par * 512 + r * 128 + (nt0 + 1) * 16 + u16],
                                           dB[r], __ATOMIC_RELAXED, __HIP_MEMORY_SCOPE_AGENT);
                }
            }
        }
        hop_begin(seq + 1);
        if (wv < 3)   // overlap: U0·h0(ts) for next step
            ua0 = mm_k(&sh[0][0][0] + ch4 * 128 + kg * 4,
                       lu0 + (wv * 16 + u16) * 264 + kg * 8, 8, z4);
        hop_end(seq + 1); ++seq;

        if (doDense) {
            // gather summed pred -> sx0 (next x0), write out slice, zero other parity
            {
                int cc = t >> 6, p = t & 63;
                float v0 = __hip_atomic_load(&g_predf[par * 512 + cc * 128 + 2 * p],
                                             __ATOMIC_RELAXED, __HIP_MEMORY_SCOPE_AGENT);
                float v1 = __hip_atomic_load(&g_predf[par * 512 + cc * 128 + 2 * p + 1],
                                             __ATOMIC_RELAXED, __HIP_MEMORY_SCOPE_AGENT);
                v0 += sbdf[2 * p]; v1 += sbdf[2 * p + 1];
                sx0[cc][p] = pk(v0, v1);
                if ((p & 3) == ((w & 3) * 0 + 0) && false) {}   // (no-op; keep structure simple)
            }
            if (t < 32) {
                int cc = t >> 3, dd = (w << 3) + (t & 7);
                float v = __hip_atomic_load(&g_predf[par * 512 + cc * 128 + dd],
                                            __ATOMIC_RELAXED, __HIP_MEMORY_SCOPE_AGENT) + sbdf[dd];
                out[((size_t)(grp * NCH + cc) * T_OUT + (ts - (T_IN - 1))) * D_ + dd] = v;
            }
            // zero the parity buffer everyone finished reading one step ago
            for (int idx = t; idx < 512; idx += THREADS)
                __hip_atomic_store(&g_predf[(par ^ 1) * 512 + idx], 0.0f,
                                   __ATOMIC_RELAXED, __HIP_MEMORY_SCOPE_AGENT);
            __syncthreads();
        }
    }
}

// ---- fallback: round-1 verified fp32 kernel (tiny/absent ws) ----
__global__ __launch_bounds__(768) void gru_ar_fp32(
    const float* __restrict__ inputs, const float* __restrict__ noise,
    const float* __restrict__ h_init,
    const float* __restrict__ W0, const float* __restrict__ U0, const float* __restrict__ b0,
    const float* __restrict__ W1, const float* __restrict__ U1, const float* __restrict__ b1,
    const float* __restrict__ W2, const float* __restrict__ U2, const float* __restrict__ b2,
    const float* __restrict__ Wd, const float* __restrict__ bd,
    float* __restrict__ out)
{
    const int b = blockIdx.x;
    const int j = threadIdx.x;
    __shared__ float s_x[U_];
    __shared__ float s_h[3][U_];
    __shared__ float s_gz[U_], s_gr[U_], s_gxn[U_], s_ghn[U_];
    __shared__ float s_pred[D_];
    if (j < U_) {
        s_h[0][j] = h_init[0 * U_ + j];
        s_h[1][j] = h_init[1 * U_ + j];
        s_h[2][j] = h_init[2 * U_ + j];
    }
    __syncthreads();
    const float* Ws[3]  = {W0, W1, W2};
    const float* Us[3]  = {U0, U1, U2};
    const float* bss[3] = {b0, b1, b2};
    for (int ts = 0; ts < NSTEP; ++ts) {
        if (j < D_) {
            if (ts < T_IN) {
                const int idx = (b * T_IN + ts) * D_ + j;
                s_x[j] = inputs[idx] + noise[idx];
            } else s_x[j] = s_pred[j];
        }
        __syncthreads();
        #pragma unroll
        for (int l = 0; l < 3; ++l) {
            const int K = (l == 0) ? D_ : U_;
            const float* W = Ws[l]; const float* Urec = Us[l]; const float* bias = bss[l];
            float gx = bias[j];
            for (int k = 0; k < K; ++k) gx = fmaf(s_x[k], W[k * 768 + j], gx);
            float gh = bias[768 + j];
            for (int k = 0; k < U_; ++k) gh = fmaf(s_h[l][k], Urec[k * 768 + j], gh);
            if (j < U_)            s_gz[j] = gx + gh;
            else if (j < 2 * U_)   s_gr[j - U_] = gx + gh;
            else { s_gxn[j - 2 * U_] = gx; s_ghn[j - 2 * U_] = gh; }
            __syncthreads();
            if (j < U_) {
                const float z = sigmoidf_(s_gz[j]);
                const float r = sigmoidf_(s_gr[j]);
                const float n = tanhf(s_gxn[j] + r * s_ghn[j]);
                const float h_new = z * s_h[l][j] + (1.0f - z) * n;
                s_h[l][j] = h_new;
                s_x[j] = (l == 0) ? h_new : (h_new + s_x[j]);
            }
            __syncthreads();
        }
        if (ts >= T_IN - 1) {
            if (j < D_) {
                float p = bd[j];
                for (int k = 0; k < U_; ++k) p = fmaf(s_x[k], Wd[k * D_ + j], p);
                s_pred[j] = p;
                out[(b * T_OUT + (ts - (T_IN - 1))) * D_ + j] = p;
            }
            __syncthreads();
        }
    }
}

extern "C" void kernel_launch(void* const* d_in, const int* in_sizes, int n_in,
                              void* d_out, int out_size, void* d_ws, size_t ws_size,
                              hipStream_t stream) {
    (void)in_sizes; (void)n_in; (void)out_size;
    const float* inputs = (const float*)d_in[0];
    const float* noise  = (const float*)d_in[1];
    const float* h_init = (const float*)d_in[2];
    const float* W0 = (const float*)d_in[3];
    const float* U0 = (const float*)d_in[4];
    const float* b0 = (const float*)d_in[5];
    const float* W1 = (const float*)d_in[6];
    const float* U1 = (const float*)d_in[7];
    const float* b1 = (const float*)d_in[8];
    const float* W2 = (const float*)d_in[9];
    const float* U2 = (const float*)d_in[10];
    const float* b2 = (const float*)d_in[11];
    const float* Wd = (const float*)d_in[12];
    const float* bd = (const float*)d_in[13];
    float* out = (float*)d_out;

    if (ws_size >= (size_t)WS_NEED) {
        const int n = NGRP * GRPSTRIDE;
        zero_ws<<<(n + 255) / 256, 256, 0, stream>>>((unsigned*)d_ws, n);
        gru_dist<<<NGRP * NWG, THREADS, 0, stream>>>(
            inputs, noise, h_init, W0, U0, b0, W1, U1, b1, W2, U2, b2, Wd, bd,
            (unsigned*)d_ws, out);
    } else {
        gru_ar_fp32<<<32, 768, 0, stream>>>(
            inputs, noise, h_init, W0, U0, b0, W1, U1, b1, W2, U2, b2, Wd, bd, out);
    }
}

// Round 5
// 5701.375 us; speedup vs baseline: 3.5050x; 1.1126x over previous
//
#include <hip/hip_runtime.h>
#include <math.h>

// Problem constants
#define T_IN   256
#define T_OUT  256
#define D_     128
#define U_     256
#define NSTEP  511

// 16 groups x 2 chains; 16 WGs per group; 256 threads/WG; 256 WGs total (1/CU)
#define NWG    16
#define NCH    2
#define NGRP   16
#define THREADS 256

// ws per group (u32 units, stride 4096 = 16KB):
//  [0..63]      barrier counter (word 0) + pad
//  [64..1599]   g_hw: warmup parity h  [2 par][3 layer][2 ch][128 pairs]
//  [1600..2367] g_har: AR h            [3 layer][2 ch][128 pairs]
//  [2368..2879] g_pred: fp32 partials  [2 par][2 ch][128]
#define OFF_CNT  0
#define OFF_HW   64
#define OFF_HAR  1600
#define OFF_PRED 2368
#define GRPSTRIDE 4096
#define WS_NEED   (NGRP * GRPSTRIDE * 4)

typedef _Float16 half8 __attribute__((ext_vector_type(8)));
typedef float    f32x4 __attribute__((ext_vector_type(4)));

__device__ __forceinline__ float sigmoidf_(float x) { return 1.0f / (1.0f + __expf(-x)); }
__device__ __forceinline__ unsigned pk(float a, float b) {
    union { _Float16 h[2]; unsigned u; } v;
    v.h[0] = (_Float16)a; v.h[1] = (_Float16)b; return v.u;
}
__device__ __forceinline__ float2 upk(unsigned x) {
    union { unsigned u; _Float16 h[2]; } v; v.u = x;
    return make_float2((float)v.h[0], (float)v.h[1]);
}

__global__ void zero_ws(unsigned* p, int n) {
    int i = blockIdx.x * 256 + threadIdx.x;
    if (i < n) p[i] = 0;
}

// K-accumulating MFMA helper (A rows = chains via u16&1 on caller side).
__device__ __forceinline__ f32x4 mm_k(const unsigned* xb, const _Float16* wb,
                                      int nks, f32x4 acc) {
    #pragma unroll
    for (int ks = 0; ks < nks; ++ks) {
        half8 a = *(const half8*)(const void*)(xb + ks * 16);
        half8 b = *(const half8*)(const void*)(wb + ks * 32);
        acc = __builtin_amdgcn_mfma_f32_16x16x32_f16(a, b, acc, 0, 0, 0);
    }
    return acc;
}

__global__ __launch_bounds__(THREADS) void gru_dist(
    const float* __restrict__ inputs, const float* __restrict__ noise,
    const float* __restrict__ h_init,
    const float* __restrict__ W0, const float* __restrict__ U0, const float* __restrict__ b0,
    const float* __restrict__ W1, const float* __restrict__ U1, const float* __restrict__ b1,
    const float* __restrict__ W2, const float* __restrict__ U2, const float* __restrict__ b2,
    const float* __restrict__ Wd, const float* __restrict__ bd,
    unsigned* __restrict__ ws, float* __restrict__ out)
{
    const int bid  = blockIdx.x;
    const int grp  = bid & 15;      // 16 WGs of a group share bid%16 -> same XCD (heuristic)
    const int w    = bid >> 4;      // wg-in-group 0..15
    const int t    = threadIdx.x;
    const int lane = t & 63;
    const int wv   = t >> 6;
    const int u16  = lane & 15, kg = lane >> 4, ch2 = u16 & 1;

    // ---- LDS (~161 KB) ----
    __shared__ __align__(16) _Float16 lw0[48 * 136];
    __shared__ __align__(16) _Float16 lu0[48 * 264];
    __shared__ __align__(16) _Float16 lw1[48 * 264];
    __shared__ __align__(16) _Float16 lu1[48 * 264];
    __shared__ __align__(16) _Float16 lw2[48 * 264];
    __shared__ __align__(16) _Float16 lu2[48 * 264];
    __shared__ __align__(16) _Float16 lwdk[128 * 32];  // [n][own-k 0..31], k>=16 zero
    __shared__ __align__(16) _Float16 sxd[16 * 32];    // dense A (rows 0,1 = chains)
    __shared__ __align__(16) unsigned sx0[NCH][68];    // x0 pairs (64) + pad
    __shared__ __align__(16) unsigned sh0[2][NCH][132];// h0, parity-double-buffered
    __shared__ __align__(16) unsigned sh1[NCH][132];
    __shared__ __align__(16) unsigned sh2[NCH][132];
    __shared__ __align__(16) unsigned sx2[NCH][132];   // x2 = h0 + h1
    __shared__ float sgx[3][192];                      // [(gate*16+lu)*4 + row]
    __shared__ float sgh[3][192];
    __shared__ float sb[3][2][48];
    __shared__ float sbdf[128];

    unsigned* gbase = ws + grp * GRPSTRIDE;
    unsigned* gcnt  = gbase + OFF_CNT;
    unsigned* g_hw  = gbase + OFF_HW;
    unsigned* g_har = gbase + OFF_HAR;
    float*    g_pred = (float*)(gbase + OFF_PRED);

    // ---- one-time preload ----
    {
        const float* srcs[6] = {W0, U0, W1, U1, W2, U2};
        _Float16*    dsts[6] = {lw0, lu0, lw1, lu1, lw2, lu2};
        const int Ks[6] = {128, 256, 256, 256, 256, 256};
        const int Ss[6] = {136, 264, 264, 264, 264, 264};
        for (int m = 0; m < 6; ++m) {
            const float* s = srcs[m]; _Float16* d = dsts[m];
            const int K = Ks[m], S = Ss[m];
            for (int idx = t; idx < 48 * K; idx += THREADS) {
                int c = idx / K, k = idx - c * K;
                int g = ((c >> 4) << 8) + (w << 4) + (c & 15);
                d[c * S + k] = (_Float16)s[k * 768 + g];
            }
        }
        for (int idx = t; idx < 128 * 32; idx += THREADS) {
            int n = idx >> 5, k = idx & 31;
            lwdk[idx] = (k < 16) ? (_Float16)Wd[(w * 16 + k) * 128 + n] : (_Float16)0.f;
        }
        for (int idx = t; idx < 16 * 32; idx += THREADS) sxd[idx] = (_Float16)0.f;
        const float* bsrc[3] = {b0, b1, b2};
        for (int idx = t; idx < 288; idx += THREADS) {
            int l = idx / 96, r = idx - l * 96, which = r / 48, c = r - which * 48;
            int g = ((c >> 4) << 8) + (w << 4) + (c & 15);
            sb[l][which][c] = bsrc[l][which * 768 + g];
        }
        for (int idx = t; idx < 128; idx += THREADS) sbdf[idx] = bd[idx];
        for (int idx = t; idx < 2 * 128; idx += THREADS) {
            int cc = idx >> 7, p = idx & 127;
            unsigned v0 = pk(h_init[0 * 256 + 2 * p], h_init[0 * 256 + 2 * p + 1]);
            sh0[0][cc][p] = v0; sh0[1][cc][p] = v0;
            sh1[cc][p] = pk(h_init[1 * 256 + 2 * p], h_init[1 * 256 + 2 * p + 1]);
            sh2[cc][p] = pk(h_init[2 * 256 + 2 * p], h_init[2 * 256 + 2 * p + 1]);
        }
    }
    // finalize threads: t<48, layer = t>>4; own unit-pair state in regs
    float hrA = 0.f, hrB = 0.f;
    if (t < 48) {
        int l = t >> 4, pl = t & 7;
        hrA = h_init[l * 256 + (w * 16 + 2 * pl)];
        hrB = h_init[l * 256 + (w * 16 + 2 * pl) + 1];
    }
    __syncthreads();

    unsigned seq = 0;
    auto bar_arrive = [&]() {
        ++seq;
        __syncthreads();   // per-wave vmcnt(0) drain before s_barrier
        if (t == 0)
            __hip_atomic_fetch_add(gcnt, 1u, __ATOMIC_RELEASE, __HIP_MEMORY_SCOPE_AGENT);
    };
    auto bar_wait = [&]() {
        if (t == 0) {
            unsigned it = 0;
            while (__hip_atomic_load(gcnt, __ATOMIC_RELAXED, __HIP_MEMORY_SCOPE_AGENT)
                   < (unsigned)NWG * seq) {
                if (++it > (1u << 22)) break;   // loud corruption beats a hang
                __builtin_amdgcn_s_sleep(1);
            }
        }
        if (t < 64) __builtin_amdgcn_fence(__ATOMIC_ACQUIRE, "agent");
        __syncthreads();
    };
    auto gather15 = [&](const unsigned* gsrc, unsigned (*lds)[132]) {
        for (int idx = t; idx < 240; idx += THREADS) {
            int i = idx >> 4, rem = idx & 15, cc = rem >> 3, pl = rem & 7;
            int src = i + (i >= w);
            int gpi = src * 8 + pl;
            lds[cc][gpi] = __hip_atomic_load(gsrc + cc * 128 + gpi,
                                             __ATOMIC_RELAXED, __HIP_MEMORY_SCOPE_AGENT);
        }
    };
    auto store_g = [&](int l, f32x4 wa, f32x4 ua) {
        if (lane < 16) {
            #pragma unroll
            for (int r = 0; r < 2; ++r) {
                sgx[l][(wv * 16 + u16) * 4 + r] = wa[r];
                sgh[l][(wv * 16 + u16) * 4 + r] = ua[r];
            }
        }
    };
    // finalize for layer l (runs on threads t>>4 == l)
    auto do_final = [&](int l, unsigned (*ldst)[132], unsigned* gdst, unsigned* gdst2,
                        bool dox3) {
        if ((t >> 4) == l) {
            int cc = (t >> 3) & 1, pl = t & 7, gpi = w * 8 + pl;
            float hn2[2];
            float hcur[2] = {hrA, hrB};
            #pragma unroll
            for (int i = 0; i < 2; ++i) {
                int lu = 2 * pl + i;
                float gxz = sgx[l][(0 * 16 + lu) * 4 + cc] + sb[l][0][lu];
                float ghz = sgh[l][(0 * 16 + lu) * 4 + cc] + sb[l][1][lu];
                float gxr = sgx[l][(1 * 16 + lu) * 4 + cc] + sb[l][0][16 + lu];
                float ghr = sgh[l][(1 * 16 + lu) * 4 + cc] + sb[l][1][16 + lu];
                float gxn = sgx[l][(2 * 16 + lu) * 4 + cc] + sb[l][0][32 + lu];
                float ghn = sgh[l][(2 * 16 + lu) * 4 + cc] + sb[l][1][32 + lu];
                float z = sigmoidf_(gxz + ghz);
                float r = sigmoidf_(gxr + ghr);
                float n = tanhf(gxn + r * ghn);
                hn2[i] = z * hcur[i] + (1.f - z) * n;
            }
            // NOTE: each (cc) thread owns the same unit-pair for its chain;
            // register state must be per-chain: cc=0 thread holds chain0, cc=1 chain1.
            hrA = hn2[0]; hrB = hn2[1];
            unsigned pv = pk(hn2[0], hn2[1]);
            ldst[cc][gpi] = pv;
            __hip_atomic_store(gdst + cc * 128 + gpi, pv,
                               __ATOMIC_RELAXED, __HIP_MEMORY_SCOPE_AGENT);
            if (gdst2)
                __hip_atomic_store(gdst2 + cc * 128 + gpi, pv,
                                   __ATOMIC_RELAXED, __HIP_MEMORY_SCOPE_AGENT);
            if (dox3) {
                float2 x2p = upk(sx2[cc][gpi]);
                sxd[cc * 32 + 2 * pl]     = (_Float16)(hn2[0] + x2p.x);
                sxd[cc * 32 + 2 * pl + 1] = (_Float16)(hn2[1] + x2p.y);
            }
        }
    };
    auto dense_add = [&](int par) {
        half8 a = *(const half8*)(const void*)(sxd + u16 * 32 + kg * 8);
        int nt0 = 2 * wv;
        half8 bA = *(const half8*)(const void*)(lwdk + (nt0 * 16 + u16) * 32 + kg * 8);
        half8 bB = *(const half8*)(const void*)(lwdk + ((nt0 + 1) * 16 + u16) * 32 + kg * 8);
        f32x4 z4l = {0.f, 0.f, 0.f, 0.f};
        f32x4 dA = __builtin_amdgcn_mfma_f32_16x16x32_f16(a, bA, z4l, 0, 0, 0);
        f32x4 dB = __builtin_amdgcn_mfma_f32_16x16x32_f16(a, bB, z4l, 0, 0, 0);
        if (lane < 16) {
            #pragma unroll
            for (int r = 0; r < 2; ++r) {
                __hip_atomic_fetch_add(&g_pred[par * 256 + r * 128 + nt0 * 16 + u16],
                                       dA[r], __ATOMIC_RELAXED, __HIP_MEMORY_SCOPE_AGENT);
                __hip_atomic_fetch_add(&g_pred[par * 256 + r * 128 + (nt0 + 1) * 16 + u16],
                                       dB[r], __ATOMIC_RELAXED, __HIP_MEMORY_SCOPE_AGENT);
            }
        }
    };
    auto pred_to_sx0 = [&](int par, int row) {
        if (t < 128) {
            int cc = t >> 6, p = t & 63;
            float v0 = __hip_atomic_load(&g_pred[par * 256 + cc * 128 + 2 * p],
                                         __ATOMIC_RELAXED, __HIP_MEMORY_SCOPE_AGENT)
                       + sbdf[2 * p];
            float v1 = __hip_atomic_load(&g_pred[par * 256 + cc * 128 + 2 * p + 1],
                                         __ATOMIC_RELAXED, __HIP_MEMORY_SCOPE_AGENT)
                       + sbdf[2 * p + 1];
            sx0[cc][p] = pk(v0, v1);
        }
        if (t < 16) {
            int cc = t >> 3, dd = w * 8 + (t & 7);
            float v = __hip_atomic_load(&g_pred[par * 256 + cc * 128 + dd],
                                        __ATOMIC_RELAXED, __HIP_MEMORY_SCOPE_AGENT) + sbdf[dd];
            out[((size_t)(grp * NCH + cc) * T_OUT + row) * D_ + dd] = v;
            __hip_atomic_store((unsigned*)&g_pred[(par ^ 1) * 256 + w * 16 + (t & 15)], 0u,
                               __ATOMIC_RELAXED, __HIP_MEMORY_SCOPE_AGENT);
        }
    };

    const f32x4 z4 = {0.f, 0.f, 0.f, 0.f};
    f32x4 ua0 = z4, ua1 = z4, ua2 = z4;

    // initial x0(0)
    if (t < 128) {
        int cc = t >> 6, p = t & 63;
        const float* ip = inputs + ((size_t)(grp * NCH + cc) * T_IN + 0) * D_ + 2 * p;
        const float* np = noise  + ((size_t)(grp * NCH + cc) * T_IN + 0) * D_ + 2 * p;
        sx0[cc][p] = pk(ip[0] + np[0], ip[1] + np[1]);
    }
    __syncthreads();

    // ================= PIPELINED WARMUP (+2 drain beats) =================
    // beat b computes: h0(b) [b<256], h1(b-1) [1<=b<=256], h2(b-2) [b>=2]
    for (int b = 0; b <= 257; ++b) {
        const int pcur = b & 1, pprev = (b + 1) & 1;
        if (wv < 3) {
            if (b < 256) {   // layer 0: W0*x0(b) + U0*h0(b-1)
                f32x4 wa = mm_k(&sx0[0][0] + ch2 * 68 + kg * 4,
                                lw0 + (wv * 16 + u16) * 136 + kg * 8, 4, z4);
                f32x4 ua = mm_k(&sh0[pprev][0][0] + ch2 * 132 + kg * 4,
                                lu0 + (wv * 16 + u16) * 264 + kg * 8, 8, z4);
                store_g(0, wa, ua);
            }
            if (b >= 1 && b <= 256) {   // layer 1: x1(b-1)=h0(b-1), h1(b-2)
                f32x4 wa = mm_k(&sh0[pprev][0][0] + ch2 * 132 + kg * 4,
                                lw1 + (wv * 16 + u16) * 264 + kg * 8, 8, z4);
                f32x4 ua = mm_k(&sh1[0][0] + ch2 * 132 + kg * 4,
                                lu1 + (wv * 16 + u16) * 264 + kg * 8, 8, z4);
                store_g(1, wa, ua);
            }
            if (b >= 2) {   // layer 2: x2(b-2), h2(b-3)
                f32x4 wa = mm_k(&sx2[0][0] + ch2 * 132 + kg * 4,
                                lw2 + (wv * 16 + u16) * 264 + kg * 8, 8, z4);
                f32x4 ua = mm_k(&sh2[0][0] + ch2 * 132 + kg * 4,
                                lu2 + (wv * 16 + u16) * 264 + kg * 8, 8, z4);
                store_g(2, wa, ua);
            }
        }
        __syncthreads();
        // finalize + publish (parity slots; h2(255) also to AR slot)
        if (b < 256)            do_final(0, sh0[pcur], g_hw + pcur * 768 + 0,   nullptr, false);
        if (b >= 1 && b <= 256) do_final(1, sh1,       g_hw + pcur * 768 + 256, nullptr, false);
        if (b >= 2)             do_final(2, sh2,       g_hw + pcur * 768 + 512,
                                         (b == 257) ? (g_har + 512) : nullptr, b == 257);
        if (b == 257) {         // dense for pred0 (parity 1 = step 255)
            __syncthreads();
            dense_add(1);
        }
        bar_arrive();
        // overlap: prefetch next input
        float i0 = 0.f, i1 = 0.f;
        if (b + 1 < 256 && t < 128) {
            int cc = t >> 6, p = t & 63;
            const float* ip = inputs + ((size_t)(grp * NCH + cc) * T_IN + (b + 1)) * D_ + 2 * p;
            const float* np = noise  + ((size_t)(grp * NCH + cc) * T_IN + (b + 1)) * D_ + 2 * p;
            i0 = ip[0] + np[0]; i1 = ip[1] + np[1];
        }
        bar_wait();
        // gathers (parity slots)
        if (b < 256)            gather15(g_hw + pcur * 768 + 0,   sh0[pcur]);
        if (b >= 1 && b <= 256) gather15(g_hw + pcur * 768 + 256, sh1);
        if (b >= 2)             gather15(g_hw + pcur * 768 + 512, sh2);
        if (b + 1 < 256 && t < 128) sx0[t >> 6][t & 63] = pk(i0, i1);
        __syncthreads();
        if (b >= 1 && b <= 256) {   // sx2 = x2(b-1) = h0(b-1) + h1(b-1)
            int cc = t >> 7, p = t & 127;
            float2 a = upk(sh0[pprev][cc][p]);
            float2 bb = upk(sh1[cc][p]);
            sx2[cc][p] = pk(a.x + bb.x, a.y + bb.y);
            __syncthreads();
        }
        if (b == 257) {   // AR entry: pred0 -> sx0, out row 0, ua0 = U0*h0(255)
            pred_to_sx0(1, 0);
            if (wv < 3)
                ua0 = mm_k(&sh0[1][0][0] + ch2 * 132 + kg * 4,
                           lu0 + (wv * 16 + u16) * 264 + kg * 8, 8, z4);
            __syncthreads();
        }
    }

    // ================= AR PHASE (serial, 3 barriers/step) =================
    for (int ts = T_IN; ts < NSTEP; ++ts) {
        const int par = ts & 1;
        // ---- layer 0 ----
        if (wv < 3) {
            f32x4 wa = mm_k(&sx0[0][0] + ch2 * 68 + kg * 4,
                            lw0 + (wv * 16 + u16) * 136 + kg * 8, 4, z4);
            store_g(0, wa, ua0);
        }
        __syncthreads();
        do_final(0, sh0[1], g_har + 0, nullptr, false);
        bar_arrive();
        if (wv < 3)
            ua1 = mm_k(&sh1[0][0] + ch2 * 132 + kg * 4,
                       lu1 + (wv * 16 + u16) * 264 + kg * 8, 8, z4);
        gather15(g_har + 512, sh2);   // deferred h2(ts-1)
        bar_wait();
        gather15(g_har + 0, sh0[1]);
        __syncthreads();
        // ---- layer 1 ----
        if (wv < 3) {
            f32x4 wa = mm_k(&sh0[1][0][0] + ch2 * 132 + kg * 4,
                            lw1 + (wv * 16 + u16) * 264 + kg * 8, 8, z4);
            store_g(1, wa, ua1);
        }
        __syncthreads();
        do_final(1, sh1, g_har + 256, nullptr, false);
        bar_arrive();
        if (wv < 3)
            ua2 = mm_k(&sh2[0][0] + ch2 * 132 + kg * 4,
                       lu2 + (wv * 16 + u16) * 264 + kg * 8, 8, z4);
        bar_wait();
        gather15(g_har + 256, sh1);
        __syncthreads();
        {   // sx2 = x2(ts) = h0(ts) + h1(ts)
            int cc = t >> 7, p = t & 127;
            float2 a = upk(sh0[1][cc][p]);
            float2 bb = upk(sh1[cc][p]);
            sx2[cc][p] = pk(a.x + bb.x, a.y + bb.y);
        }
        __syncthreads();
        // ---- layer 2 + dense ----
        if (wv < 3) {
            f32x4 wa = mm_k(&sx2[0][0] + ch2 * 132 + kg * 4,
                            lw2 + (wv * 16 + u16) * 264 + kg * 8, 8, z4);
            store_g(2, wa, ua2);
        }
        __syncthreads();
        do_final(2, sh2, g_har + 512, nullptr, true);
        __syncthreads();
        dense_add(par);
        bar_arrive();
        if (wv < 3)
            ua0 = mm_k(&sh0[1][0][0] + ch2 * 132 + kg * 4,
                       lu0 + (wv * 16 + u16) * 264 + kg * 8, 8, z4);
        bar_wait();
        pred_to_sx0(par, ts - (T_IN - 1));
        __syncthreads();
    }
}

// ---- fallback: round-1 verified fp32 kernel (tiny/absent ws) ----
__global__ __launch_bounds__(768) void gru_ar_fp32(
    const float* __restrict__ inputs, const float* __restrict__ noise,
    const float* __restrict__ h_init,
    const float* __restrict__ W0, const float* __restrict__ U0, const float* __restrict__ b0,
    const float* __restrict__ W1, const float* __restrict__ U1, const float* __restrict__ b1,
    const float* __restrict__ W2, const float* __restrict__ U2, const float* __restrict__ b2,
    const float* __restrict__ Wd, const float* __restrict__ bd,
    float* __restrict__ out)
{
    const int b = blockIdx.x;
    const int j = threadIdx.x;
    __shared__ float s_x[U_];
    __shared__ float s_h[3][U_];
    __shared__ float s_gz[U_], s_gr[U_], s_gxn[U_], s_ghn[U_];
    __shared__ float s_pred[D_];
    if (j < U_) {
        s_h[0][j] = h_init[0 * U_ + j];
        s_h[1][j] = h_init[1 * U_ + j];
        s_h[2][j] = h_init[2 * U_ + j];
    }
    __syncthreads();
    const float* Ws[3]  = {W0, W1, W2};
    const float* Us[3]  = {U0, U1, U2};
    const float* bss[3] = {b0, b1, b2};
    for (int ts = 0; ts < NSTEP; ++ts) {
        if (j < D_) {
            if (ts < T_IN) {
                const int idx = (b * T_IN + ts) * D_ + j;
                s_x[j] = inputs[idx] + noise[idx];
            } else s_x[j] = s_pred[j];
        }
        __syncthreads();
        #pragma unroll
        for (int l = 0; l < 3; ++l) {
            const int K = (l == 0) ? D_ : U_;
            const float* W = Ws[l]; const float* Urec = Us[l]; const float* bias = bss[l];
            float gx = bias[j];
            for (int k = 0; k < K; ++k) gx = fmaf(s_x[k], W[k * 768 + j], gx);
            float gh = bias[768 + j];
            for (int k = 0; k < U_; ++k) gh = fmaf(s_h[l][k], Urec[k * 768 + j], gh);
            if (j < U_)            s_gz[j] = gx + gh;
            else if (j < 2 * U_)   s_gr[j - U_] = gx + gh;
            else { s_gxn[j - 2 * U_] = gx; s_ghn[j - 2 * U_] = gh; }
            __syncthreads();
            if (j < U_) {
                const float z = sigmoidf_(s_gz[j]);
                const float r = sigmoidf_(s_gr[j]);
                const float n = tanhf(s_gxn[j] + r * s_ghn[j]);
                const float h_new = z * s_h[l][j] + (1.0f - z) * n;
                s_h[l][j] = h_new;
                s_x[j] = (l == 0) ? h_new : (h_new + s_x[j]);
            }
            __syncthreads();
        }
        if (ts >= T_IN - 1) {
            if (j < D_) {
                float p = bd[j];
                for (int k = 0; k < U_; ++k) p = fmaf(s_x[k], Wd[k * D_ + j], p);
                s_pred[j] = p;
                out[(b * T_OUT + (ts - (T_IN - 1))) * D_ + j] = p;
            }
            __syncthreads();
        }
    }
}

extern "C" void kernel_launch(void* const* d_in, const int* in_sizes, int n_in,
                              void* d_out, int out_size, void* d_ws, size_t ws_size,
                              hipStream_t stream) {
    (void)in_sizes; (void)n_in; (void)out_size;
    const float* inputs = (const float*)d_in[0];
    const float* noise  = (const float*)d_in[1];
    const float* h_init = (const float*)d_in[2];
    const float* W0 = (const float*)d_in[3];
    const float* U0 = (const float*)d_in[4];
    const float* b0 = (const float*)d_in[5];
    const float* W1 = (const float*)d_in[6];
    const float* U1 = (const float*)d_in[7];
    const float* b1 = (const float*)d_in[8];
    const float* W2 = (const float*)d_in[9];
    const float* U2 = (const float*)d_in[10];
    const float* b2 = (const float*)d_in[11];
    const float* Wd = (const float*)d_in[12];
    const float* bd = (const float*)d_in[13];
    float* out = (float*)d_out;

    if (ws_size >= (size_t)WS_NEED) {
        const int n = NGRP * GRPSTRIDE;
        zero_ws<<<(n + 255) / 256, 256, 0, stream>>>((unsigned*)d_ws, n);
        gru_dist<<<NGRP * NWG, THREADS, 0, stream>>>(
            inputs, noise, h_init, W0, U0, b0, W1, U1, b1, W2, U2, b2, Wd, bd,
            (unsigned*)d_ws, out);
    } else {
        gru_ar_fp32<<<32, 768, 0, stream>>>(
            inputs, noise, h_init, W0, U0, b0, W1, U1, b1, W2, U2, b2, Wd, bd, out);
    }
}

// Round 6
// 3520.680 us; speedup vs baseline: 5.6760x; 1.6194x over previous
//
#include <hip/hip_runtime.h>
#include <math.h>

// Problem constants
#define T_IN   256
#define T_OUT  256
#define D_     128
#define U_     256
#define NSTEP  511

// 16 groups x 2 chains; 16 WGs per group; 256 threads/WG; 256 WGs total (1/CU)
#define NWG    16
#define NCH    2
#define NGRP   16
#define THREADS 256

// ws per group in u64 units (tagged words: hi32 = tag, lo32 = payload):
//   g_h0 [2 slot][2 ch][128]  @ 0
//   g_h1                      @ 512
//   g_h2                      @ 1024
//   g_pd [2 slot][16 src][2 ch][128] @ 1536   (fp32 dense partials)
#define G64_H0   0
#define G64_H1   512
#define G64_H2   1024
#define G64_PD   1536
#define GRPSTRIDE64 10240
#define WS_NEED  (NGRP * GRPSTRIDE64 * 8)   // 1,310,720 B (ws_size >= 2.23MB known ok)

typedef _Float16 half8 __attribute__((ext_vector_type(8)));
typedef float    f32x4 __attribute__((ext_vector_type(4)));

__device__ __forceinline__ float sigmoidf_(float x) { return 1.0f / (1.0f + __expf(-x)); }
__device__ __forceinline__ unsigned pk(float a, float b) {
    union { _Float16 h[2]; unsigned u; } v;
    v.h[0] = (_Float16)a; v.h[1] = (_Float16)b; return v.u;
}
__device__ __forceinline__ float2 upk(unsigned x) {
    union { unsigned u; _Float16 h[2]; } v; v.u = x;
    return make_float2((float)v.h[0], (float)v.h[1]);
}

__global__ void zero_ws(unsigned* p, int n) {
    int i = blockIdx.x * 256 + threadIdx.x;
    if (i < n) p[i] = 0;
}

__device__ __forceinline__ f32x4 mm_k(const unsigned* xb, const _Float16* wb,
                                      int nks, f32x4 acc) {
    #pragma unroll
    for (int ks = 0; ks < nks; ++ks) {
        half8 a = *(const half8*)(const void*)(xb + ks * 16);
        half8 b = *(const half8*)(const void*)(wb + ks * 32);
        acc = __builtin_amdgcn_mfma_f32_16x16x32_f16(a, b, acc, 0, 0, 0);
    }
    return acc;
}

__global__ __launch_bounds__(THREADS) void gru_dist(
    const float* __restrict__ inputs, const float* __restrict__ noise,
    const float* __restrict__ h_init,
    const float* __restrict__ W0, const float* __restrict__ U0, const float* __restrict__ b0,
    const float* __restrict__ W1, const float* __restrict__ U1, const float* __restrict__ b1,
    const float* __restrict__ W2, const float* __restrict__ U2, const float* __restrict__ b2,
    const float* __restrict__ Wd, const float* __restrict__ bd,
    unsigned long long* __restrict__ ws, float* __restrict__ out)
{
    const int bid  = blockIdx.x;
    const int grp  = bid & 15;      // groups interleaved so a group's WGs share an XCD (heuristic)
    const int w    = bid >> 4;      // wg-in-group 0..15
    const int t    = threadIdx.x;
    const int lane = t & 63;
    const int wv   = t >> 6;
    const int u16  = lane & 15, kg = lane >> 4, ch2 = u16 & 1;

    // ---- LDS (~158 KB) ----
    __shared__ __align__(16) _Float16 lw0[48 * 136];
    __shared__ __align__(16) _Float16 lu0[48 * 264];
    __shared__ __align__(16) _Float16 lw1[48 * 264];
    __shared__ __align__(16) _Float16 lu1[48 * 264];
    __shared__ __align__(16) _Float16 lw2[48 * 264];
    __shared__ __align__(16) _Float16 lu2[48 * 264];
    __shared__ __align__(16) _Float16 lwdk[128 * 32];  // [n][own-k 0..31], k>=16 zero
    __shared__ __align__(16) _Float16 sxd[16 * 32];    // dense A (rows 0,1 = chains)
    __shared__ __align__(16) unsigned sx0[NCH][68];
    __shared__ __align__(16) unsigned sh0[2][NCH][132];
    __shared__ __align__(16) unsigned sh1[NCH][132];
    __shared__ __align__(16) unsigned sh2[NCH][132];
    __shared__ __align__(16) unsigned sx2[NCH][132];
    __shared__ float sgx[3][192];
    __shared__ float sgh[3][192];
    __shared__ float sb[3][2][48];
    __shared__ float sbdf[128];
    __shared__ float spredf[NCH][128];

    unsigned long long* gbase = ws + (size_t)grp * GRPSTRIDE64;
    unsigned long long* g_h0 = gbase + G64_H0;
    unsigned long long* g_h1 = gbase + G64_H1;
    unsigned long long* g_h2 = gbase + G64_H2;
    unsigned long long* g_pd = gbase + G64_PD;

    // ---- one-time preload ----
    {
        const float* srcs[6] = {W0, U0, W1, U1, W2, U2};
        _Float16*    dsts[6] = {lw0, lu0, lw1, lu1, lw2, lu2};
        const int Ks[6] = {128, 256, 256, 256, 256, 256};
        const int Ss[6] = {136, 264, 264, 264, 264, 264};
        for (int m = 0; m < 6; ++m) {
            const float* s = srcs[m]; _Float16* d = dsts[m];
            const int K = Ks[m], S = Ss[m];
            for (int idx = t; idx < 48 * K; idx += THREADS) {
                int c = idx / K, k = idx - c * K;
                int g = ((c >> 4) << 8) + (w << 4) + (c & 15);
                d[c * S + k] = (_Float16)s[k * 768 + g];
            }
        }
        for (int idx = t; idx < 128 * 32; idx += THREADS) {
            int n = idx >> 5, k = idx & 31;
            lwdk[idx] = (k < 16) ? (_Float16)Wd[(w * 16 + k) * 128 + n] : (_Float16)0.f;
        }
        for (int idx = t; idx < 16 * 32; idx += THREADS) sxd[idx] = (_Float16)0.f;
        const float* bsrc[3] = {b0, b1, b2};
        for (int idx = t; idx < 288; idx += THREADS) {
            int l = idx / 96, r = idx - l * 96, which = r / 48, c = r - which * 48;
            int g = ((c >> 4) << 8) + (w << 4) + (c & 15);
            sb[l][which][c] = bsrc[l][which * 768 + g];
        }
        for (int idx = t; idx < 128; idx += THREADS) sbdf[idx] = bd[idx];
        for (int idx = t; idx < 2 * 128; idx += THREADS) {
            int cc = idx >> 7, p = idx & 127;
            unsigned v0 = pk(h_init[0 * 256 + 2 * p], h_init[0 * 256 + 2 * p + 1]);
            sh0[0][cc][p] = v0; sh0[1][cc][p] = v0;
            sh1[cc][p] = pk(h_init[1 * 256 + 2 * p], h_init[1 * 256 + 2 * p + 1]);
            sh2[cc][p] = pk(h_init[2 * 256 + 2 * p], h_init[2 * 256 + 2 * p + 1]);
        }
    }
    // finalize threads: t<48, layer = t>>4, chain = (t>>3)&1, unit-pair = t&7
    float hrA = 0.f, hrB = 0.f;
    if (t < 48) {
        int l = t >> 4, pl = t & 7;
        hrA = h_init[l * 256 + (w * 16 + 2 * pl)];
        hrB = h_init[l * 256 + (w * 16 + 2 * pl) + 1];
    }
    __syncthreads();

    // ---- tagged-P2P primitives (1 IF round-trip per comm round) ----
    auto gather_tagged = [&](const unsigned long long* garr, unsigned (*lds)[132],
                             unsigned tag) {
        const unsigned long long* base = garr + (tag & 1) * 256;
        for (int idx = t; idx < 240; idx += THREADS) {
            int i = idx >> 4, rem = idx & 15, cc = rem >> 3, pl = rem & 7;
            int src = i + (i >= w);
            int gpi = src * 8 + pl;
            const unsigned long long* p = base + cc * 128 + gpi;
            unsigned long long v = __hip_atomic_load(p, __ATOMIC_RELAXED,
                                                     __HIP_MEMORY_SCOPE_AGENT);
            unsigned it = 0;
            while ((unsigned)(v >> 32) < tag) {
                __builtin_amdgcn_s_sleep(1);
                v = __hip_atomic_load(p, __ATOMIC_RELAXED, __HIP_MEMORY_SCOPE_AGENT);
                if (++it > (1u << 20)) break;   // loud corruption beats a hang
            }
            lds[cc][gpi] = (unsigned)v;
        }
    };
    auto store_g = [&](int l, f32x4 wa, f32x4 ua) {
        if (lane < 16) {
            #pragma unroll
            for (int r = 0; r < 2; ++r) {
                sgx[l][(wv * 16 + u16) * 4 + r] = wa[r];
                sgh[l][(wv * 16 + u16) * 4 + r] = ua[r];
            }
        }
    };
    // finalize layer l on threads (t>>4)==l; publish = single tagged u64 store
    auto do_final = [&](int l, unsigned (*ldst)[132], unsigned long long* garr,
                        unsigned tag, bool dox3) {
        if ((t >> 4) == l) {
            int cc = (t >> 3) & 1, pl = t & 7, gpi = w * 8 + pl;
            float hn2[2];
            float hcur[2] = {hrA, hrB};
            #pragma unroll
            for (int i = 0; i < 2; ++i) {
                int lu = 2 * pl + i;
                float gxz = sgx[l][(0 * 16 + lu) * 4 + cc] + sb[l][0][lu];
                float ghz = sgh[l][(0 * 16 + lu) * 4 + cc] + sb[l][1][lu];
                float gxr = sgx[l][(1 * 16 + lu) * 4 + cc] + sb[l][0][16 + lu];
                float ghr = sgh[l][(1 * 16 + lu) * 4 + cc] + sb[l][1][16 + lu];
                float gxn = sgx[l][(2 * 16 + lu) * 4 + cc] + sb[l][0][32 + lu];
                float ghn = sgh[l][(2 * 16 + lu) * 4 + cc] + sb[l][1][32 + lu];
                float z = sigmoidf_(gxz + ghz);
                float r = sigmoidf_(gxr + ghr);
                float n = tanhf(gxn + r * ghn);
                hn2[i] = z * hcur[i] + (1.f - z) * n;
            }
            hrA = hn2[0]; hrB = hn2[1];
            unsigned pv = pk(hn2[0], hn2[1]);
            ldst[cc][gpi] = pv;
            __hip_atomic_store(garr + (tag & 1) * 256 + cc * 128 + gpi,
                               ((unsigned long long)tag << 32) | (unsigned long long)pv,
                               __ATOMIC_RELAXED, __HIP_MEMORY_SCOPE_AGENT);
            if (dox3) {
                float2 x2p = upk(sx2[cc][gpi]);
                sxd[cc * 32 + 2 * pl]     = (_Float16)(hn2[0] + x2p.x);
                sxd[cc * 32 + 2 * pl + 1] = (_Float16)(hn2[1] + x2p.y);
            }
        }
    };
    auto dense_pub = [&](unsigned tag) {
        half8 a = *(const half8*)(const void*)(sxd + u16 * 32 + kg * 8);
        int nt0 = 2 * wv;
        half8 bA = *(const half8*)(const void*)(lwdk + (nt0 * 16 + u16) * 32 + kg * 8);
        half8 bB = *(const half8*)(const void*)(lwdk + ((nt0 + 1) * 16 + u16) * 32 + kg * 8);
        f32x4 z4l = {0.f, 0.f, 0.f, 0.f};
        f32x4 dA = __builtin_amdgcn_mfma_f32_16x16x32_f16(a, bA, z4l, 0, 0, 0);
        f32x4 dB = __builtin_amdgcn_mfma_f32_16x16x32_f16(a, bB, z4l, 0, 0, 0);
        if (lane < 16) {
            unsigned long long* base = g_pd + (tag & 1) * 4096 + (unsigned)w * 256;
            #pragma unroll
            for (int r = 0; r < 2; ++r) {
                union { float f; unsigned u; } cA, cB;
                cA.f = dA[r]; cB.f = dB[r];
                __hip_atomic_store(base + r * 128 + nt0 * 16 + u16,
                                   ((unsigned long long)tag << 32) | cA.u,
                                   __ATOMIC_RELAXED, __HIP_MEMORY_SCOPE_AGENT);
                __hip_atomic_store(base + r * 128 + (nt0 + 1) * 16 + u16,
                                   ((unsigned long long)tag << 32) | cB.u,
                                   __ATOMIC_RELAXED, __HIP_MEMORY_SCOPE_AGENT);
            }
        }
    };
    auto pred_gather = [&](unsigned tag, int row) {
        const int cc = t >> 7, o = t & 127;
        const unsigned long long* base = g_pd + (tag & 1) * 4096 + cc * 128 + o;
        float s = sbdf[o];
        for (int src = 0; src < 16; ++src) {
            const unsigned long long* p = base + src * 256;
            unsigned long long v = __hip_atomic_load(p, __ATOMIC_RELAXED,
                                                     __HIP_MEMORY_SCOPE_AGENT);
            unsigned it = 0;
            while ((unsigned)(v >> 32) < tag) {
                __builtin_amdgcn_s_sleep(1);
                v = __hip_atomic_load(p, __ATOMIC_RELAXED, __HIP_MEMORY_SCOPE_AGENT);
                if (++it > (1u << 20)) break;
            }
            union { unsigned u; float f; } cv; cv.u = (unsigned)v;
            s += cv.f;
        }
        spredf[cc][o] = s;
        __syncthreads();
        if (t < 128) {
            int c2 = t >> 6, p2 = t & 63;
            sx0[c2][p2] = pk(spredf[c2][2 * p2], spredf[c2][2 * p2 + 1]);
        }
        if (t < 16) {
            int c2 = t >> 3, dd = w * 8 + (t & 7);
            out[((size_t)(grp * NCH + c2) * T_OUT + row) * D_ + dd] = spredf[c2][dd];
        }
    };

    const f32x4 z4 = {0.f, 0.f, 0.f, 0.f};
    f32x4 ua0 = z4, ua1 = z4, ua2 = z4;

    // initial x0(0)
    if (t < 128) {
        int cc = t >> 6, p = t & 63;
        const float* ip = inputs + ((size_t)(grp * NCH + cc) * T_IN + 0) * D_ + 2 * p;
        const float* np = noise  + ((size_t)(grp * NCH + cc) * T_IN + 0) * D_ + 2 * p;
        sx0[cc][p] = pk(ip[0] + np[0], ip[1] + np[1]);
    }
    __syncthreads();

    // ================= PIPELINED WARMUP (+2 drain beats) =================
    // beat b: h0(b) [b<256], h1(b-1) [1<=b<=256], h2(b-2) [b>=2]
    // tags: h0(s) -> s+1, h1(s) -> s+1, h2(s) -> s+1; slot = tag&1
    for (int b = 0; b <= 257; ++b) {
        const int pcur = b & 1, pprev = (b + 1) & 1;
        if (wv < 3) {
            if (b < 256) {
                f32x4 wa = mm_k(&sx0[0][0] + ch2 * 68 + kg * 4,
                                lw0 + (wv * 16 + u16) * 136 + kg * 8, 4, z4);
                f32x4 ua = mm_k(&sh0[pprev][0][0] + ch2 * 132 + kg * 4,
                                lu0 + (wv * 16 + u16) * 264 + kg * 8, 8, z4);
                store_g(0, wa, ua);
            }
            if (b >= 1 && b <= 256) {
                f32x4 wa = mm_k(&sh0[pprev][0][0] + ch2 * 132 + kg * 4,
                                lw1 + (wv * 16 + u16) * 264 + kg * 8, 8, z4);
                f32x4 ua = mm_k(&sh1[0][0] + ch2 * 132 + kg * 4,
                                lu1 + (wv * 16 + u16) * 264 + kg * 8, 8, z4);
                store_g(1, wa, ua);
            }
            if (b >= 2) {
                f32x4 wa = mm_k(&sx2[0][0] + ch2 * 132 + kg * 4,
                                lw2 + (wv * 16 + u16) * 264 + kg * 8, 8, z4);
                f32x4 ua = mm_k(&sh2[0][0] + ch2 * 132 + kg * 4,
                                lu2 + (wv * 16 + u16) * 264 + kg * 8, 8, z4);
                store_g(2, wa, ua);
            }
        }
        __syncthreads();
        // finalize + tagged publish
        if (b < 256)            do_final(0, sh0[pcur], g_h0, (unsigned)(b + 1), false);
        if (b >= 1 && b <= 256) do_final(1, sh1, g_h1, (unsigned)b, false);
        if (b >= 2)             do_final(2, sh2, g_h2, (unsigned)(b - 1), b == 257);
        // input prefetch (hides HBM under poll)
        float i0 = 0.f, i1 = 0.f;
        if (b + 1 < 256 && t < 128) {
            int cc = t >> 6, p = t & 63;
            const float* ip = inputs + ((size_t)(grp * NCH + cc) * T_IN + (b + 1)) * D_ + 2 * p;
            const float* np = noise  + ((size_t)(grp * NCH + cc) * T_IN + (b + 1)) * D_ + 2 * p;
            i0 = ip[0] + np[0]; i1 = ip[1] + np[1];
        }
        // poll-gathers (data rides with the tag word)
        if (b < 256)            gather_tagged(g_h0, sh0[pcur], (unsigned)(b + 1));
        if (b >= 1 && b <= 256) gather_tagged(g_h1, sh1, (unsigned)b);
        if (b >= 2)             gather_tagged(g_h2, sh2, (unsigned)(b - 1));
        if (b + 1 < 256 && t < 128) sx0[t >> 6][t & 63] = pk(i0, i1);
        __syncthreads();
        if (b >= 1 && b <= 256) {   // sx2 = x2(b-1) = h0(b-1) + h1(b-1)
            int cc = t >> 7, p = t & 127;
            float2 a = upk(sh0[pprev][cc][p]);
            float2 bb = upk(sh1[cc][p]);
            sx2[cc][p] = pk(a.x + bb.x, a.y + bb.y);
            __syncthreads();
        }
        if (b == 257) {   // dense for pred(255) (tag 1), AR entry
            dense_pub(1);
            if (wv < 3)
                ua0 = mm_k(&sh0[1][0][0] + ch2 * 132 + kg * 4,
                           lu0 + (wv * 16 + u16) * 264 + kg * 8, 8, z4);
            pred_gather(1, 0);
            __syncthreads();
        }
    }

    // ================= AR PHASE (3 tagged rounds/step) =================
    for (int ts = T_IN; ts < NSTEP; ++ts) {
        const unsigned ht = (unsigned)(ts + 1);     // h tag this step
        const unsigned pt = (unsigned)(ts - 254);   // pred tag
        // ---- round A: layer 0 ----
        if (wv < 3) {
            f32x4 wa = mm_k(&sx0[0][0] + ch2 * 68 + kg * 4,
                            lw0 + (wv * 16 + u16) * 136 + kg * 8, 4, z4);
            store_g(0, wa, ua0);
        }
        __syncthreads();
        do_final(0, sh0[1], g_h0, ht, false);
        if (wv < 3)   // overlap: U1*h1(ts-1)
            ua1 = mm_k(&sh1[0][0] + ch2 * 132 + kg * 4,
                       lu1 + (wv * 16 + u16) * 264 + kg * 8, 8, z4);
        gather_tagged(g_h2, sh2, ht - 1);   // deferred h2(ts-1)
        gather_tagged(g_h0, sh0[1], ht);
        __syncthreads();
        // ---- round B: layer 1 ----
        if (wv < 3) {
            f32x4 wa = mm_k(&sh0[1][0][0] + ch2 * 132 + kg * 4,
                            lw1 + (wv * 16 + u16) * 264 + kg * 8, 8, z4);
            store_g(1, wa, ua1);
        }
        __syncthreads();
        do_final(1, sh1, g_h1, ht, false);
        if (wv < 3)   // overlap: U2*h2(ts-1)
            ua2 = mm_k(&sh2[0][0] + ch2 * 132 + kg * 4,
                       lu2 + (wv * 16 + u16) * 264 + kg * 8, 8, z4);
        gather_tagged(g_h1, sh1, ht);
        __syncthreads();
        {   // sx2 = h0(ts) + h1(ts)
            int cc = t >> 7, p = t & 127;
            float2 a = upk(sh0[1][cc][p]);
            float2 bb = upk(sh1[cc][p]);
            sx2[cc][p] = pk(a.x + bb.x, a.y + bb.y);
        }
        __syncthreads();
        // ---- round C: layer 2 + K-split dense ----
        if (wv < 3) {
            f32x4 wa = mm_k(&sx2[0][0] + ch2 * 132 + kg * 4,
                            lw2 + (wv * 16 + u16) * 264 + kg * 8, 8, z4);
            store_g(2, wa, ua2);
        }
        __syncthreads();
        do_final(2, sh2, g_h2, ht, true);
        __syncthreads();   // sxd visible
        dense_pub(pt);
        if (wv < 3)   // overlap: U0*h0(ts) for next step
            ua0 = mm_k(&sh0[1][0][0] + ch2 * 132 + kg * 4,
                       lu0 + (wv * 16 + u16) * 264 + kg * 8, 8, z4);
        pred_gather(pt, ts - 255);
        __syncthreads();
    }
}

// ---- fallback: round-1 verified fp32 kernel (tiny/absent ws) ----
__global__ __launch_bounds__(768) void gru_ar_fp32(
    const float* __restrict__ inputs, const float* __restrict__ noise,
    const float* __restrict__ h_init,
    const float* __restrict__ W0, const float* __restrict__ U0, const float* __restrict__ b0,
    const float* __restrict__ W1, const float* __restrict__ U1, const float* __restrict__ b1,
    const float* __restrict__ W2, const float* __restrict__ U2, const float* __restrict__ b2,
    const float* __restrict__ Wd, const float* __restrict__ bd,
    float* __restrict__ out)
{
    const int b = blockIdx.x;
    const int j = threadIdx.x;
    __shared__ float s_x[U_];
    __shared__ float s_h[3][U_];
    __shared__ float s_gz[U_], s_gr[U_], s_gxn[U_], s_ghn[U_];
    __shared__ float s_pred[D_];
    if (j < U_) {
        s_h[0][j] = h_init[0 * U_ + j];
        s_h[1][j] = h_init[1 * U_ + j];
        s_h[2][j] = h_init[2 * U_ + j];
    }
    __syncthreads();
    const float* Ws[3]  = {W0, W1, W2};
    const float* Us[3]  = {U0, U1, U2};
    const float* bss[3] = {b0, b1, b2};
    for (int ts = 0; ts < NSTEP; ++ts) {
        if (j < D_) {
            if (ts < T_IN) {
                const int idx = (b * T_IN + ts) * D_ + j;
                s_x[j] = inputs[idx] + noise[idx];
            } else s_x[j] = s_pred[j];
        }
        __syncthreads();
        #pragma unroll
        for (int l = 0; l < 3; ++l) {
            const int K = (l == 0) ? D_ : U_;
            const float* W = Ws[l]; const float* Urec = Us[l]; const float* bias = bss[l];
            float gx = bias[j];
            for (int k = 0; k < K; ++k) gx = fmaf(s_x[k], W[k * 768 + j], gx);
            float gh = bias[768 + j];
            for (int k = 0; k < U_; ++k) gh = fmaf(s_h[l][k], Urec[k * 768 + j], gh);
            if (j < U_)            s_gz[j] = gx + gh;
            else if (j < 2 * U_)   s_gr[j - U_] = gx + gh;
            else { s_gxn[j - 2 * U_] = gx; s_ghn[j - 2 * U_] = gh; }
            __syncthreads();
            if (j < U_) {
                const float z = sigmoidf_(s_gz[j]);
                const float r = sigmoidf_(s_gr[j]);
                const float n = tanhf(s_gxn[j] + r * s_ghn[j]);
                const float h_new = z * s_h[l][j] + (1.0f - z) * n;
                s_h[l][j] = h_new;
                s_x[j] = (l == 0) ? h_new : (h_new + s_x[j]);
            }
            __syncthreads();
        }
        if (ts >= T_IN - 1) {
            if (j < D_) {
                float p = bd[j];
                for (int k = 0; k < U_; ++k) p = fmaf(s_x[k], Wd[k * D_ + j], p);
                s_pred[j] = p;
                out[(b * T_OUT + (ts - (T_IN - 1))) * D_ + j] = p;
            }
            __syncthreads();
        }
    }
}

extern "C" void kernel_launch(void* const* d_in, const int* in_sizes, int n_in,
                              void* d_out, int out_size, void* d_ws, size_t ws_size,
                              hipStream_t stream) {
    (void)in_sizes; (void)n_in; (void)out_size;
    const float* inputs = (const float*)d_in[0];
    const float* noise  = (const float*)d_in[1];
    const float* h_init = (const float*)d_in[2];
    const float* W0 = (const float*)d_in[3];
    const float* U0 = (const float*)d_in[4];
    const float* b0 = (const float*)d_in[5];
    const float* W1 = (const float*)d_in[6];
    const float* U1 = (const float*)d_in[7];
    const float* b1 = (const float*)d_in[8];
    const float* W2 = (const float*)d_in[9];
    const float* U2 = (const float*)d_in[10];
    const float* b2 = (const float*)d_in[11];
    const float* Wd = (const float*)d_in[12];
    const float* bd = (const float*)d_in[13];
    float* out = (float*)d_out;

    if (ws_size >= (size_t)WS_NEED) {
        const int n = NGRP * GRPSTRIDE64 * 2;   // u32 words
        zero_ws<<<(n + 255) / 256, 256, 0, stream>>>((unsigned*)d_ws, n);
        gru_dist<<<NGRP * NWG, THREADS, 0, stream>>>(
            inputs, noise, h_init, W0, U0, b0, W1, U1, b1, W2, U2, b2, Wd, bd,
            (unsigned long long*)d_ws, out);
    } else {
        gru_ar_fp32<<<32, 768, 0, stream>>>(
            inputs, noise, h_init, W0, U0, b0, W1, U1, b1, W2, U2, b2, Wd, bd, out);
    }
}